// Round 1
// baseline (1315.920 us; speedup 1.0000x reference)
//
#include <hip/hip_runtime.h>
#include <cstdint>

// Additive attention pooling, fused single-pass with online softmax.
// B=256 blocks (one per batch), 16 waves/block.
// Each wave processes RG=4 consecutive rows per iteration (block covers a
// contiguous 64-row / 128 KiB window per round), with a 4-row-deep register
// prefetch and DPP-based (LDS-free) 64-lane reductions.

#define NW    16            // waves per block
#define BLOCK (NW * 64)     // 1024 threads
#define UDIM  512
#define RG    4             // rows per wave per iteration
#define TSTEP (NW * RG)     // 64 rows per block round

// 64-lane sum via DPP: row_shr 1/2/4/8 within 16-lane rows, then
// row_bcast:15 (rows 1,3) and row_bcast:31 (rows 2,3). Total lands in
// lane 63; broadcast back via readlane. Pure VALU, no LDS/lgkmcnt.
__device__ __forceinline__ float dpp_sum64(float x) {
    int t;
    t = __builtin_amdgcn_update_dpp(0, __float_as_int(x), 0x111, 0xf, 0xf, true); x += __int_as_float(t); // row_shr:1
    t = __builtin_amdgcn_update_dpp(0, __float_as_int(x), 0x112, 0xf, 0xf, true); x += __int_as_float(t); // row_shr:2
    t = __builtin_amdgcn_update_dpp(0, __float_as_int(x), 0x114, 0xf, 0xf, true); x += __int_as_float(t); // row_shr:4
    t = __builtin_amdgcn_update_dpp(0, __float_as_int(x), 0x118, 0xf, 0xf, true); x += __int_as_float(t); // row_shr:8
    t = __builtin_amdgcn_update_dpp(0, __float_as_int(x), 0x142, 0xa, 0xf, true); x += __int_as_float(t); // row_bcast:15
    t = __builtin_amdgcn_update_dpp(0, __float_as_int(x), 0x143, 0xc, 0xf, true); x += __int_as_float(t); // row_bcast:31
    return __int_as_float(__builtin_amdgcn_readlane(__float_as_int(x), 63));
}

__device__ __forceinline__ float dot4(float4 a, float4 b) {
    return fmaf(a.x, b.x, fmaf(a.y, b.y, fmaf(a.z, b.z, a.w * b.w)));
}
__device__ __forceinline__ float4 f4fma(float s, float4 a, float4 c) {
    return make_float4(fmaf(s, a.x, c.x), fmaf(s, a.y, c.y),
                       fmaf(s, a.z, c.z), fmaf(s, a.w, c.w));
}
__device__ __forceinline__ float4 f4scale(float4 a, float s) {
    return make_float4(a.x * s, a.y * s, a.z * s, a.w * s);
}

__global__ __launch_bounds__(BLOCK, 1)
void attn_pool_fused(const float* __restrict__ x,
                     const float* __restrict__ Wv,
                     const float* __restrict__ bv,
                     float* __restrict__ out, int T) {
    const int bidx = blockIdx.x;
    const int tid  = threadIdx.x;
    const int w    = tid >> 6;     // wave id 0..NW-1
    const int lane = tid & 63;
    const int u0   = lane << 3;    // 8 floats per lane

    // Per-lane W fragment (loaded once).
    const float4* wp = (const float4*)(Wv + u0);
    const float4  wA = wp[0];
    const float4  wB = wp[1];

    const float* xb = x + (size_t)bidx * (size_t)T * UDIM;

    // Online-softmax state. Scores are tanh-bounded in (-1,1), so m=-1 is a
    // valid lower bound -> no -inf handling needed.
    float  m = -1.0f, l = 0.0f;
    float4 oA = make_float4(0.f, 0.f, 0.f, 0.f);
    float4 oB = make_float4(0.f, 0.f, 0.f, 0.f);

    // Current / next row groups (RG rows x 2 float4 each). Fully unrolled ->
    // static indexing only (no scratch).
    float4 cc[RG][2], nn[RG][2];

    int tb = w * RG;
    {
        const float* p = xb + (size_t)tb * UDIM + u0;
        #pragma unroll
        for (int r = 0; r < RG; ++r) {
            cc[r][0] = ((const float4*)p)[0];
            cc[r][1] = ((const float4*)p)[1];
            p += UDIM;
        }
    }

    const int iters = T / TSTEP;   // 2048/64 = 32
    for (int i = 0; i < iters; ++i) {
        // Prefetch next group (branchless clamp on last iter).
        const int tn = tb + TSTEP;
        const int tf = (i + 1 < iters) ? tn : tb;
        {
            const float* p = xb + (size_t)tf * UDIM + u0;
            #pragma unroll
            for (int r = 0; r < RG; ++r) {
                nn[r][0] = ((const float4*)p)[0];
                nn[r][1] = ((const float4*)p)[1];
                p += UDIM;
            }
        }

        // Bias for the 4 consecutive rows (tb % 4 == 0 -> aligned float4).
        const float4 bvv = *(const float4*)(bv + tb);

        // 4 independent partial dots, then 4 interleaved DPP reduction chains.
        float d0 = dot4(cc[0][0], wA) + dot4(cc[0][1], wB);
        float d1 = dot4(cc[1][0], wA) + dot4(cc[1][1], wB);
        float d2 = dot4(cc[2][0], wA) + dot4(cc[2][1], wB);
        float d3 = dot4(cc[3][0], wA) + dot4(cc[3][1], wB);
        d0 = dpp_sum64(d0);
        d1 = dpp_sum64(d1);
        d2 = dpp_sum64(d2);
        d3 = dpp_sum64(d3);

        // tanh(s) = 1 - 2/(e^{2s}+1); rcp approx error ~1e-7 rel, negligible.
        float s0 = d0 + bvv.x, s1 = d1 + bvv.y, s2 = d2 + bvv.z, s3 = d3 + bvv.w;
        float e0 = 1.0f - 2.0f * __builtin_amdgcn_rcpf(__expf(2.0f * s0) + 1.0f);
        float e1 = 1.0f - 2.0f * __builtin_amdgcn_rcpf(__expf(2.0f * s1) + 1.0f);
        float e2 = 1.0f - 2.0f * __builtin_amdgcn_rcpf(__expf(2.0f * s2) + 1.0f);
        float e3 = 1.0f - 2.0f * __builtin_amdgcn_rcpf(__expf(2.0f * s3) + 1.0f);

        // Grouped online-softmax update: one rescale per 4 rows (exact).
        const float gm = fmaxf(fmaxf(e0, e1), fmaxf(e2, e3));
        const float mn = fmaxf(m, gm);
        const float sc = __expf(m - mn);
        const float p0 = __expf(e0 - mn);
        const float p1 = __expf(e1 - mn);
        const float p2 = __expf(e2 - mn);
        const float p3 = __expf(e3 - mn);
        l = fmaf(l, sc, (p0 + p1) + (p2 + p3));
        oA = f4scale(oA, sc);
        oB = f4scale(oB, sc);
        oA = f4fma(p0, cc[0][0], oA);  oB = f4fma(p0, cc[0][1], oB);
        oA = f4fma(p1, cc[1][0], oA);  oB = f4fma(p1, cc[1][1], oB);
        oA = f4fma(p2, cc[2][0], oA);  oB = f4fma(p2, cc[2][1], oB);
        oA = f4fma(p3, cc[3][0], oA);  oB = f4fma(p3, cc[3][1], oB);
        m = mn;

        #pragma unroll
        for (int r = 0; r < RG; ++r) {
            cc[r][0] = nn[r][0];
            cc[r][1] = nn[r][1];
        }
        tb = tn;
    }

    // Merge the NW per-wave online-softmax states through LDS.
    __shared__ float sm_m[NW];
    __shared__ float sm_l[NW];
    __shared__ float sm_o[NW][UDIM];   // 32 KiB
    if (lane == 0) { sm_m[w] = m; sm_l[w] = l; }
    float4* so = (float4*)&sm_o[w][u0];
    so[0] = oA;
    so[1] = oB;
    __syncthreads();

    if (tid < UDIM) {
        float M = -1.0f;
        #pragma unroll
        for (int j = 0; j < NW; ++j) M = fmaxf(M, sm_m[j]);
        float L = 0.0f, acc = 0.0f;
        #pragma unroll
        for (int j = 0; j < NW; ++j) {
            float s = __expf(sm_m[j] - M);
            L   += s * sm_l[j];
            acc += s * sm_o[j][tid];
        }
        out[(size_t)bidx * UDIM + tid] = acc / L;
    }
}

extern "C" void kernel_launch(void* const* d_in, const int* in_sizes, int n_in,
                              void* d_out, int out_size, void* d_ws, size_t ws_size,
                              hipStream_t stream) {
    const float* x  = (const float*)d_in[0];   // (B, T, U) fp32
    const float* W  = (const float*)d_in[1];   // (U, 1)    fp32
    const float* bb = (const float*)d_in[2];   // (T, 1)    fp32
    float* out      = (float*)d_out;           // (B, U)    fp32

    const int U = in_sizes[1];                 // 512
    const int T = in_sizes[2];                 // 2048
    const int B = in_sizes[0] / (T * U);       // 256
    (void)U; (void)n_in; (void)out_size; (void)d_ws; (void)ws_size;

    attn_pool_fused<<<B, BLOCK, 0, stream>>>(x, W, bb, out, T);
}